// Round 1
// baseline (2400.452 us; speedup 1.0000x reference)
//
#include <hip/hip_runtime.h>

typedef unsigned short u16;
typedef unsigned int   u32;

typedef __attribute__((ext_vector_type(8))) short bf16x8;
typedef __attribute__((ext_vector_type(4))) float f32x4;

// ---------- helpers ----------
__device__ __forceinline__ u16 f2bf(float v) {           // RNE fp32 -> bf16
    u32 u = __float_as_uint(v);
    u32 r = (u + 0x7fffu + ((u >> 16) & 1u)) >> 16;
    return (u16)r;
}
__device__ __forceinline__ float bf2f(u16 h) { return __uint_as_float(((u32)h) << 16); }

__device__ __forceinline__ void gl2lds16(const void* g, void* l) {
    __builtin_amdgcn_global_load_lds(
        (const __attribute__((address_space(1))) void*)g,
        (__attribute__((address_space(3))) void*)l, 16, 0, 0);
}

// ---------- init: zero h buffers and r chain ----------
__global__ void init_k(u16* __restrict__ hh, u16* __restrict__ hl, float* __restrict__ rb) {
    int i = blockIdx.x * 256 + threadIdx.x;           // grid covers 12*512*512
    hh[i] = 0; hl[i] = 0;
    if (i < 13 * 512) rb[i] = 0.0f;
}

// ---------- pack W: W4t[n][k] = W_gate[k][col], hi/lo bf16 split; bias4[n] ----------
__global__ void pack_w(const float* __restrict__ Wf, const float* __restrict__ bf_,
                       const float* __restrict__ Wi, const float* __restrict__ bi_,
                       const float* __restrict__ Wo, const float* __restrict__ bo_,
                       const float* __restrict__ Wg, const float* __restrict__ bg_,
                       u16* __restrict__ wth, u16* __restrict__ wtl, float* __restrict__ bias4) {
    int idx = blockIdx.x * 256 + threadIdx.x;         // 2048*768 threads, wave-uniform n (768=12*64)
    int n = idx / 768, k = idx - n * 768;
    int gate = n >> 9, col = n & 511;
    const float* W = (gate == 0) ? Wf : (gate == 1) ? Wi : (gate == 2) ? Wo : Wg;
    float v = W[k * 512 + col];
    u16 h = f2bf(v);
    wth[idx] = h;
    wtl[idx] = f2bf(v - bf2f(h));
    if (k == 0) {
        const float* bb = (gate == 0) ? bf_ : (gate == 1) ? bi_ : (gate == 2) ? bo_ : bg_;
        bias4[n] = bb[col];
    }
}

// ---------- split x block to hi/lo bf16 ----------
__global__ void split_x(const float* __restrict__ src, u16* __restrict__ oh, u16* __restrict__ ol) {
    int i = blockIdx.x * 256 + threadIdx.x;           // grid covers S*512*256/4
    float4 v = ((const float4*)src)[i];
    u16 hx = f2bf(v.x), hy = f2bf(v.y), hz = f2bf(v.z), hw = f2bf(v.w);
    u16 lx = f2bf(v.x - bf2f(hx)), ly = f2bf(v.y - bf2f(hy));
    u16 lz = f2bf(v.z - bf2f(hz)), lw = f2bf(v.w - bf2f(hw));
    uint2 hv; hv.x = (u32)hx | ((u32)hy << 16); hv.y = (u32)hz | ((u32)hw << 16);
    uint2 lv; lv.x = (u32)lx | ((u32)ly << 16); lv.y = (u32)lz | ((u32)lw << 16);
    ((uint2*)oh)[i] = hv;
    ((uint2*)ol)[i] = lv;
}

// ---------- bf16x3 GEMM: logits[m][n] = A[m][:]@W4[:, n] + bias4[n] ----------
// A[m][k<256]=x[t][b][k], A[m][256+k]=h_buf[s][b][k]; m=(s,b); 128x128 tile, BK=32
#define BK 32
__global__ __launch_bounds__(256, 2) void gemm_x3(
    const u16* __restrict__ xh, const u16* __restrict__ xl,
    const u16* __restrict__ hh, const u16* __restrict__ hl,
    const u16* __restrict__ wth, const u16* __restrict__ wtl,
    const float* __restrict__ bias4, float* __restrict__ lg) {
    __shared__ __align__(16) u16 Ah[128 * BK];
    __shared__ __align__(16) u16 Al[128 * BK];
    __shared__ __align__(16) u16 Bh[128 * BK];
    __shared__ __align__(16) u16 Bl[128 * BK];

    const int tid = threadIdx.x;
    const int wid = tid >> 6, lane = tid & 63;
    const int bn = blockIdx.x, bm = blockIdx.y;
    const int s = bm >> 2;                 // t%12 == s (t0 always multiple of 12)
    const int b0 = (bm & 3) * 128;
    const int laneR = lane >> 2;           // row within 16-row staging group
    const int laneC = (lane & 3) * 8;      // k element offset

    u16* lds = (wid == 0) ? Ah : (wid == 1) ? Al : (wid == 2) ? Bh : Bl;
    const u16* xp = (wid == 0) ? xh : xl;
    const u16* hp = (wid == 0) ? hh : hl;
    const u16* wp = (wid == 2) ? wth : wtl;
    const u16* xrow = xp + (size_t)(s * 512 + b0) * 256 + laneR * 256 + laneC;
    const u16* hrow = hp + (size_t)(s * 512 + b0) * 512 + laneR * 512 + laneC;
    const u16* wrow = wp + (size_t)(bn * 128) * 768 + laneR * 768 + laneC;

    const int wm = wid >> 1, wn = wid & 1;
    const int lm = lane & 15, quad = lane >> 4;

    f32x4 acc[4][4];
#pragma unroll
    for (int i = 0; i < 4; i++)
#pragma unroll
        for (int j = 0; j < 4; j++) { acc[i][j].x = 0.f; acc[i][j].y = 0.f; acc[i][j].z = 0.f; acc[i][j].w = 0.f; }

    for (int k0 = 0; k0 < 768; k0 += BK) {
        __syncthreads();
        if (wid < 2) {
            if (k0 < 256) {
                const u16* src = xrow + k0;
#pragma unroll
                for (int r = 0; r < 8; ++r) gl2lds16(src + r * 16 * 256, lds + r * 16 * BK);
            } else {
                const u16* src = hrow + (k0 - 256);
#pragma unroll
                for (int r = 0; r < 8; ++r) gl2lds16(src + r * 16 * 512, lds + r * 16 * BK);
            }
        } else {
            const u16* src = wrow + k0;
#pragma unroll
            for (int r = 0; r < 8; ++r) gl2lds16(src + r * 16 * 768, lds + r * 16 * BK);
        }
        __syncthreads();

        bf16x8 a_h[4], a_l[4], b_h[4], b_l[4];
#pragma unroll
        for (int i = 0; i < 4; ++i) {
            a_h[i] = *(const bf16x8*)&Ah[(wm * 64 + i * 16 + lm) * BK + quad * 8];
            a_l[i] = *(const bf16x8*)&Al[(wm * 64 + i * 16 + lm) * BK + quad * 8];
            b_h[i] = *(const bf16x8*)&Bh[(wn * 64 + i * 16 + lm) * BK + quad * 8];
            b_l[i] = *(const bf16x8*)&Bl[(wn * 64 + i * 16 + lm) * BK + quad * 8];
        }
#pragma unroll
        for (int i = 0; i < 4; ++i)
#pragma unroll
            for (int j = 0; j < 4; ++j) {
                acc[i][j] = __builtin_amdgcn_mfma_f32_16x16x32_bf16(a_h[i], b_h[j], acc[i][j], 0, 0, 0);
                acc[i][j] = __builtin_amdgcn_mfma_f32_16x16x32_bf16(a_h[i], b_l[j], acc[i][j], 0, 0, 0);
                acc[i][j] = __builtin_amdgcn_mfma_f32_16x16x32_bf16(a_l[i], b_h[j], acc[i][j], 0, 0, 0);
            }
    }

#pragma unroll
    for (int j = 0; j < 4; ++j) {
        int n = bn * 128 + wn * 64 + j * 16 + lm;
        float bv = bias4[n];
#pragma unroll
        for (int i = 0; i < 4; ++i) {
            int row = wm * 64 + i * 16 + quad * 4;
            size_t base = (size_t)(bm * 128 + row) * 2048 + n;
#pragma unroll
            for (int r = 0; r < 4; ++r) lg[base + (size_t)r * 2048] = acc[i][j][r] + bv;
        }
    }
}

// ---------- chain: single wave walks the sequential c-row recurrence ----------
__global__ void chain_k(const float* __restrict__ lg, float* __restrict__ rb, int S) {
    const int lane = threadIdx.x;  // 64 threads, 8 cols each
    float r[8];
#pragma unroll
    for (int u = 0; u < 8; ++u) r[u] = rb[12 * 512 + lane * 8 + u];
    for (int s = 0; s < S; ++s) {
#pragma unroll
        for (int u = 0; u < 8; ++u) rb[s * 512 + lane * 8 + u] = r[u];  // r_t for gates_k
        int rowb = (s + 1) % 12;   // batch row (t+1)%P of c_t
        const float* base = lg + (size_t)(s * 512 + rowb) * 2048 + lane * 8;
        float f[8], iv[8], g[8];
#pragma unroll
        for (int u = 0; u < 8; ++u) { f[u] = base[u]; iv[u] = base[512 + u]; g[u] = base[1536 + u]; }
        float mf = -1e30f, mi = -1e30f;
#pragma unroll
        for (int u = 0; u < 8; ++u) { mf = fmaxf(mf, f[u]); mi = fmaxf(mi, iv[u]); }
#pragma unroll
        for (int o = 32; o; o >>= 1) { mf = fmaxf(mf, __shfl_xor(mf, o)); mi = fmaxf(mi, __shfl_xor(mi, o)); }
        float sf = 0.f, si = 0.f;
#pragma unroll
        for (int u = 0; u < 8; ++u) {
            f[u] = __expf(f[u] - mf); sf += f[u];
            iv[u] = __expf(iv[u] - mi); si += iv[u];
        }
#pragma unroll
        for (int o = 32; o; o >>= 1) { sf += __shfl_xor(sf, o); si += __shfl_xor(si, o); }
        float rf = 1.0f / sf, ri = 1.0f / si;
#pragma unroll
        for (int u = 0; u < 8; ++u) {
            float gg = tanhf(g[u]);
            r[u] = tanhf(f[u] * rf * r[u] + iv[u] * ri * gg);
        }
    }
#pragma unroll
    for (int u = 0; u < 8; ++u) rb[12 * 512 + lane * 8 + u] = r[u];
}

// ---------- gates: softmax f,i,o + tanh g, c_new, h row (hi/lo bf16), final out ----------
__global__ __launch_bounds__(256) void gates_k(
    const float* __restrict__ lg, const float* __restrict__ rb,
    u16* __restrict__ hh, u16* __restrict__ hl,
    float* __restrict__ out, int t0) {
    const int w = (blockIdx.x * 256 + threadIdx.x) >> 6;  // one wave per (s,b) row
    const int lane = threadIdx.x & 63;
    const int s = w >> 9, b = w & 511;
    const int t = t0 + s;
    const float* row = lg + (size_t)(s * 512 + b) * 2048 + lane * 8;
    float f[8], iv[8], ov[8], g[8];
#pragma unroll
    for (int u = 0; u < 8; ++u) {
        f[u] = row[u]; iv[u] = row[512 + u]; ov[u] = row[1024 + u]; g[u] = row[1536 + u];
    }
    float mf = -1e30f, mi = -1e30f, mo = -1e30f;
#pragma unroll
    for (int u = 0; u < 8; ++u) { mf = fmaxf(mf, f[u]); mi = fmaxf(mi, iv[u]); mo = fmaxf(mo, ov[u]); }
#pragma unroll
    for (int o = 32; o; o >>= 1) {
        mf = fmaxf(mf, __shfl_xor(mf, o));
        mi = fmaxf(mi, __shfl_xor(mi, o));
        mo = fmaxf(mo, __shfl_xor(mo, o));
    }
    float sf = 0.f, si = 0.f, so = 0.f;
#pragma unroll
    for (int u = 0; u < 8; ++u) {
        f[u] = __expf(f[u] - mf); sf += f[u];
        iv[u] = __expf(iv[u] - mi); si += iv[u];
        ov[u] = __expf(ov[u] - mo); so += ov[u];
    }
#pragma unroll
    for (int o = 32; o; o >>= 1) {
        sf += __shfl_xor(sf, o); si += __shfl_xor(si, o); so += __shfl_xor(so, o);
    }
    float rf = 1.0f / sf, ri = 1.0f / si, ro = 1.0f / so;
    float hout[8];
#pragma unroll
    for (int u = 0; u < 8; ++u) {
        float rr = rb[s * 512 + lane * 8 + u];
        float gg = tanhf(g[u]);
        float cv = tanhf(f[u] * rf * rr + iv[u] * ri * gg);
        hout[u] = ov[u] * ro * cv;
    }
    u32 hhp[4], hlp[4];
#pragma unroll
    for (int u = 0; u < 4; ++u) {
        u16 h0 = f2bf(hout[2 * u]), h1 = f2bf(hout[2 * u + 1]);
        u16 l0 = f2bf(hout[2 * u] - bf2f(h0)), l1 = f2bf(hout[2 * u + 1] - bf2f(h1));
        hhp[u] = (u32)h0 | ((u32)h1 << 16);
        hlp[u] = (u32)l0 | ((u32)l1 << 16);
    }
    size_t hb = ((size_t)(s * 512 + b)) * 512 + lane * 8;   // h row index = t%12 = s
    *(uint4*)&hh[hb] = make_uint4(hhp[0], hhp[1], hhp[2], hhp[3]);
    *(uint4*)&hl[hb] = make_uint4(hlp[0], hlp[1], hlp[2], hlp[3]);
    if (t == 255) {
        float* op = out + (size_t)b * 512 + lane * 8;
#pragma unroll
        for (int u = 0; u < 8; ++u) op[u] = hout[u];
    }
}

extern "C" void kernel_launch(void* const* d_in, const int* in_sizes, int n_in,
                              void* d_out, int out_size, void* d_ws, size_t ws_size,
                              hipStream_t stream) {
    const float* x   = (const float*)d_in[0];
    const float* Wf  = (const float*)d_in[1];
    const float* bf_ = (const float*)d_in[2];
    const float* Wi  = (const float*)d_in[3];
    const float* bi_ = (const float*)d_in[4];
    const float* Wo  = (const float*)d_in[5];
    const float* bo_ = (const float*)d_in[6];
    const float* Wg  = (const float*)d_in[7];
    const float* bg_ = (const float*)d_in[8];
    float* out = (float*)d_out;

    char* p = (char*)d_ws;
    u16* xh  = (u16*)p; p += 3145728;       // [12*512, 256] bf16 hi
    u16* xl  = (u16*)p; p += 3145728;
    u16* wth = (u16*)p; p += 3145728;       // [2048, 768] bf16 hi (transposed W4)
    u16* wtl = (u16*)p; p += 3145728;
    u16* hh  = (u16*)p; p += 6291456;       // [12, 512, 512] bf16 hi
    u16* hl  = (u16*)p; p += 6291456;
    float* bias4 = (float*)p; p += 8192;    // [2048]
    float* rb    = (float*)p; p += 32768;   // [13, 512] (12 = carry slot)
    float* lg    = (float*)p; p += 50331648;// [12*512, 2048] fp32 logits

    init_k<<<12288, 256, 0, stream>>>(hh, hl, rb);
    pack_w<<<6144, 256, 0, stream>>>(Wf, bf_, Wi, bi_, Wo, bo_, Wg, bg_, wth, wtl, bias4);

    for (int blk = 0; blk < 22; ++blk) {
        int t0 = blk * 12;
        int S = (256 - t0 >= 12) ? 12 : (256 - t0);  // last block: 4 steps
        split_x<<<S * 128, 256, 0, stream>>>(x + (size_t)t0 * 512 * 256, xh, xl);
        gemm_x3<<<dim3(16, S * 4), 256, 0, stream>>>(xh, xl, hh, hl, wth, wtl, bias4, lg);
        chain_k<<<1, 64, 0, stream>>>(lg, rb, S);
        gates_k<<<S * 128, 256, 0, stream>>>(lg, rb, hh, hl, out, t0);
    }
}

// Round 2
// 2153.559 us; speedup vs baseline: 1.1146x; 1.1146x over previous
//
#include <hip/hip_runtime.h>

typedef unsigned short u16;
typedef unsigned int   u32;

typedef __attribute__((ext_vector_type(8))) short bf16x8;
typedef __attribute__((ext_vector_type(4))) float f32x4;

// ---------- helpers ----------
__device__ __forceinline__ u16 f2bf(float v) {           // RNE fp32 -> bf16
    u32 u = __float_as_uint(v);
    u32 r = (u + 0x7fffu + ((u >> 16) & 1u)) >> 16;
    return (u16)r;
}
__device__ __forceinline__ float bf2f(u16 h) { return __uint_as_float(((u32)h) << 16); }

__device__ __forceinline__ void gl2lds16(const void* g, void* l) {
    __builtin_amdgcn_global_load_lds(
        (const __attribute__((address_space(1))) void*)g,
        (__attribute__((address_space(3))) void*)l, 16, 0, 0);
}

// ---------- init: zero h buffers and carry ----------
__global__ void init_k(u16* __restrict__ hh, u16* __restrict__ hl, float* __restrict__ cb) {
    int i = blockIdx.x * 256 + threadIdx.x;           // grid covers 12*512*512
    hh[i] = 0; hl[i] = 0;
    if (i < 2 * 512) cb[i] = 0.0f;
}

// ---------- pack W: W4t[n][k] = W_gate[k][col], hi/lo bf16 split; bias4[n] ----------
__global__ void pack_w(const float* __restrict__ Wf, const float* __restrict__ bf_,
                       const float* __restrict__ Wi, const float* __restrict__ bi_,
                       const float* __restrict__ Wo, const float* __restrict__ bo_,
                       const float* __restrict__ Wg, const float* __restrict__ bg_,
                       u16* __restrict__ wth, u16* __restrict__ wtl, float* __restrict__ bias4) {
    int idx = blockIdx.x * 256 + threadIdx.x;         // 2048*768 threads, wave-uniform n (768=12*64)
    int n = idx / 768, k = idx - n * 768;
    int gate = n >> 9, col = n & 511;
    const float* W = (gate == 0) ? Wf : (gate == 1) ? Wi : (gate == 2) ? Wo : Wg;
    float v = W[k * 512 + col];
    u16 h = f2bf(v);
    wth[idx] = h;
    wtl[idx] = f2bf(v - bf2f(h));
    if (k == 0) {
        const float* bb = (gate == 0) ? bf_ : (gate == 1) ? bi_ : (gate == 2) ? bo_ : bg_;
        bias4[n] = bb[col];
    }
}

// ---------- split ALL x to hi/lo bf16 (hoisted out of the block loop) ----------
__global__ void split_x(const float* __restrict__ src, u16* __restrict__ oh, u16* __restrict__ ol) {
    int i = blockIdx.x * 256 + threadIdx.x;           // grid covers 256*512*256/4
    float4 v = ((const float4*)src)[i];
    u16 hx = f2bf(v.x), hy = f2bf(v.y), hz = f2bf(v.z), hw = f2bf(v.w);
    u16 lx = f2bf(v.x - bf2f(hx)), ly = f2bf(v.y - bf2f(hy));
    u16 lz = f2bf(v.z - bf2f(hz)), lw = f2bf(v.w - bf2f(hw));
    uint2 hv; hv.x = (u32)hx | ((u32)hy << 16); hv.y = (u32)hz | ((u32)hw << 16);
    uint2 lv; lv.x = (u32)lx | ((u32)ly << 16); lv.y = (u32)lz | ((u32)lw << 16);
    ((uint2*)oh)[i] = hv;
    ((uint2*)ol)[i] = lv;
}

// ---------- bf16x3 GEMM: logits[m][n] = A[m][:]@W4[:, n] + bias4[n] ----------
// A[m][k<256]=x[t][b][k], A[m][256+k]=h_buf[s][b][k]; m=(s,b); 128x128 tile, BK=32
#define BK 32
__global__ __launch_bounds__(256, 3) void gemm_x3(
    const u16* __restrict__ xh, const u16* __restrict__ xl,
    const u16* __restrict__ hh, const u16* __restrict__ hl,
    const u16* __restrict__ wth, const u16* __restrict__ wtl,
    const float* __restrict__ bias4, float* __restrict__ lg) {
    __shared__ __align__(16) u16 Ah[128 * BK];
    __shared__ __align__(16) u16 Al[128 * BK];
    __shared__ __align__(16) u16 Bh[128 * BK];
    __shared__ __align__(16) u16 Bl[128 * BK];

    const int tid = threadIdx.x;
    const int wid = tid >> 6, lane = tid & 63;
    const int bn = blockIdx.x, bm = blockIdx.y;
    const int s = bm >> 2;                 // t%12 == s (t0 always multiple of 12)
    const int b0 = (bm & 3) * 128;
    const int laneR = lane >> 2;           // row within 16-row staging group
    const int laneC = (lane & 3) * 8;      // k element offset

    u16* lds = (wid == 0) ? Ah : (wid == 1) ? Al : (wid == 2) ? Bh : Bl;
    const u16* xp = (wid == 0) ? xh : xl;
    const u16* hp = (wid == 0) ? hh : hl;
    const u16* wp = (wid == 2) ? wth : wtl;
    const u16* xrow = xp + (size_t)(s * 512 + b0) * 256 + laneR * 256 + laneC;
    const u16* hrow = hp + (size_t)(s * 512 + b0) * 512 + laneR * 512 + laneC;
    const u16* wrow = wp + (size_t)(bn * 128) * 768 + laneR * 768 + laneC;

    const int wm = wid >> 1, wn = wid & 1;
    const int lm = lane & 15, quad = lane >> 4;

    f32x4 acc[4][4];
#pragma unroll
    for (int i = 0; i < 4; i++)
#pragma unroll
        for (int j = 0; j < 4; j++) { acc[i][j].x = 0.f; acc[i][j].y = 0.f; acc[i][j].z = 0.f; acc[i][j].w = 0.f; }

    for (int k0 = 0; k0 < 768; k0 += BK) {
        __syncthreads();
        if (wid < 2) {
            if (k0 < 256) {
                const u16* src = xrow + k0;
#pragma unroll
                for (int r = 0; r < 8; ++r) gl2lds16(src + r * 16 * 256, lds + r * 16 * BK);
            } else {
                const u16* src = hrow + (k0 - 256);
#pragma unroll
                for (int r = 0; r < 8; ++r) gl2lds16(src + r * 16 * 512, lds + r * 16 * BK);
            }
        } else {
            const u16* src = wrow + k0;
#pragma unroll
            for (int r = 0; r < 8; ++r) gl2lds16(src + r * 16 * 768, lds + r * 16 * BK);
        }
        __syncthreads();

        bf16x8 a_h[4], a_l[4], b_h[4], b_l[4];
#pragma unroll
        for (int i = 0; i < 4; ++i) {
            a_h[i] = *(const bf16x8*)&Ah[(wm * 64 + i * 16 + lm) * BK + quad * 8];
            a_l[i] = *(const bf16x8*)&Al[(wm * 64 + i * 16 + lm) * BK + quad * 8];
            b_h[i] = *(const bf16x8*)&Bh[(wn * 64 + i * 16 + lm) * BK + quad * 8];
            b_l[i] = *(const bf16x8*)&Bl[(wn * 64 + i * 16 + lm) * BK + quad * 8];
        }
#pragma unroll
        for (int i = 0; i < 4; ++i)
#pragma unroll
            for (int j = 0; j < 4; ++j) {
                acc[i][j] = __builtin_amdgcn_mfma_f32_16x16x32_bf16(a_h[i], b_h[j], acc[i][j], 0, 0, 0);
                acc[i][j] = __builtin_amdgcn_mfma_f32_16x16x32_bf16(a_h[i], b_l[j], acc[i][j], 0, 0, 0);
                acc[i][j] = __builtin_amdgcn_mfma_f32_16x16x32_bf16(a_l[i], b_h[j], acc[i][j], 0, 0, 0);
            }
    }

#pragma unroll
    for (int j = 0; j < 4; ++j) {
        int n = bn * 128 + wn * 64 + j * 16 + lm;
        float bv = bias4[n];
#pragma unroll
        for (int i = 0; i < 4; ++i) {
            int row = wm * 64 + i * 16 + quad * 4;
            size_t base = (size_t)(bm * 128 + row) * 2048 + n;
#pragma unroll
            for (int r = 0; r < 4; ++r) lg[base + (size_t)r * 2048] = acc[i][j][r] + bv;
        }
    }
}

// ---------- one sequential chain step: r <- tanh(softmax_f[rowb]*r + softmax_i[rowb]*tanh(g[rowb])) ----------
__device__ __forceinline__ void chain_step(const float* __restrict__ lg, int j, int lane, float r[8]) {
    int rowb = (j + 1) % 12;   // batch row (t+1)%P of c_t (t0 always multiple of 12)
    const float* base = lg + (size_t)(j * 512 + rowb) * 2048 + lane * 8;
    float f[8], iv[8], g[8];
#pragma unroll
    for (int u = 0; u < 8; ++u) { f[u] = base[u]; iv[u] = base[512 + u]; g[u] = base[1536 + u]; }
    float mf = -1e30f, mi = -1e30f;
#pragma unroll
    for (int u = 0; u < 8; ++u) { mf = fmaxf(mf, f[u]); mi = fmaxf(mi, iv[u]); }
#pragma unroll
    for (int o = 32; o; o >>= 1) { mf = fmaxf(mf, __shfl_xor(mf, o)); mi = fmaxf(mi, __shfl_xor(mi, o)); }
    float sf = 0.f, si = 0.f;
#pragma unroll
    for (int u = 0; u < 8; ++u) {
        f[u] = __expf(f[u] - mf); sf += f[u];
        iv[u] = __expf(iv[u] - mi); si += iv[u];
    }
#pragma unroll
    for (int o = 32; o; o >>= 1) { sf += __shfl_xor(sf, o); si += __shfl_xor(si, o); }
    float rf = 1.0f / sf, ri = 1.0f / si;
#pragma unroll
    for (int u = 0; u < 8; ++u) {
        float gg = tanhf(g[u]);
        r[u] = tanhf(f[u] * rf * r[u] + iv[u] * ri * gg);
    }
}

// ---------- gates (chain fused): wave 0 walks chain to its block's s; then all waves do
//            softmax f,i,o + tanh g, c_new, h row (hi/lo bf16), final out ----------
__global__ __launch_bounds__(256) void gates_k(
    const float* __restrict__ lg, float* __restrict__ cb,
    u16* __restrict__ hh, u16* __restrict__ hl,
    float* __restrict__ out, int t0, int S, int rd, int wr) {
    __shared__ float rsh[512];
    const int widx = threadIdx.x >> 6, lane = threadIdx.x & 63;
    const int s = blockIdx.x >> 7;                      // 128 blocks per s (block-uniform s)
    const int b = (blockIdx.x & 127) * 4 + widx;
    const int t = t0 + s;

    if (widx == 0) {
        float r[8];
#pragma unroll
        for (int u = 0; u < 8; ++u) r[u] = cb[rd * 512 + lane * 8 + u];
        for (int j = 0; j < s; ++j) chain_step(lg, j, lane, r);   // identical op sequence in every block -> bitwise-identical r
#pragma unroll
        for (int u = 0; u < 8; ++u) rsh[lane * 8 + u] = r[u];
        // designated carrier block extends the chain one step and writes next-launch carry
        if ((int)blockIdx.x == S * 128 - 1 && t0 + S < 256) {
            chain_step(lg, s, lane, r);
#pragma unroll
            for (int u = 0; u < 8; ++u) cb[wr * 512 + lane * 8 + u] = r[u];
        }
    }
    __syncthreads();

    const float* row = lg + (size_t)(s * 512 + b) * 2048 + lane * 8;
    float f[8], iv[8], ov[8], g[8];
#pragma unroll
    for (int u = 0; u < 8; ++u) {
        f[u] = row[u]; iv[u] = row[512 + u]; ov[u] = row[1024 + u]; g[u] = row[1536 + u];
    }
    float mf = -1e30f, mi = -1e30f, mo = -1e30f;
#pragma unroll
    for (int u = 0; u < 8; ++u) { mf = fmaxf(mf, f[u]); mi = fmaxf(mi, iv[u]); mo = fmaxf(mo, ov[u]); }
#pragma unroll
    for (int o = 32; o; o >>= 1) {
        mf = fmaxf(mf, __shfl_xor(mf, o));
        mi = fmaxf(mi, __shfl_xor(mi, o));
        mo = fmaxf(mo, __shfl_xor(mo, o));
    }
    float sf = 0.f, si = 0.f, so = 0.f;
#pragma unroll
    for (int u = 0; u < 8; ++u) {
        f[u] = __expf(f[u] - mf); sf += f[u];
        iv[u] = __expf(iv[u] - mi); si += iv[u];
        ov[u] = __expf(ov[u] - mo); so += ov[u];
    }
#pragma unroll
    for (int o = 32; o; o >>= 1) {
        sf += __shfl_xor(sf, o); si += __shfl_xor(si, o); so += __shfl_xor(so, o);
    }
    float rf = 1.0f / sf, ri = 1.0f / si, ro = 1.0f / so;
    float hout[8];
#pragma unroll
    for (int u = 0; u < 8; ++u) {
        float rr = rsh[lane * 8 + u];
        float gg = tanhf(g[u]);
        float cv = tanhf(f[u] * rf * rr + iv[u] * ri * gg);
        hout[u] = ov[u] * ro * cv;
    }
    u32 hhp[4], hlp[4];
#pragma unroll
    for (int u = 0; u < 4; ++u) {
        u16 h0 = f2bf(hout[2 * u]), h1 = f2bf(hout[2 * u + 1]);
        u16 l0 = f2bf(hout[2 * u] - bf2f(h0)), l1 = f2bf(hout[2 * u + 1] - bf2f(h1));
        hhp[u] = (u32)h0 | ((u32)h1 << 16);
        hlp[u] = (u32)l0 | ((u32)l1 << 16);
    }
    size_t hb = ((size_t)(s * 512 + b)) * 512 + lane * 8;   // h row index = t%12 = s
    *(uint4*)&hh[hb] = make_uint4(hhp[0], hhp[1], hhp[2], hhp[3]);
    *(uint4*)&hl[hb] = make_uint4(hlp[0], hlp[1], hlp[2], hlp[3]);
    if (t == 255) {
        float* op = out + (size_t)b * 512 + lane * 8;
#pragma unroll
        for (int u = 0; u < 8; ++u) op[u] = hout[u];
    }
}

extern "C" void kernel_launch(void* const* d_in, const int* in_sizes, int n_in,
                              void* d_out, int out_size, void* d_ws, size_t ws_size,
                              hipStream_t stream) {
    const float* x   = (const float*)d_in[0];
    const float* Wf  = (const float*)d_in[1];
    const float* bf_ = (const float*)d_in[2];
    const float* Wi  = (const float*)d_in[3];
    const float* bi_ = (const float*)d_in[4];
    const float* Wo  = (const float*)d_in[5];
    const float* bo_ = (const float*)d_in[6];
    const float* Wg  = (const float*)d_in[7];
    const float* bg_ = (const float*)d_in[8];
    float* out = (float*)d_out;

    char* p = (char*)d_ws;
    u16* xh  = (u16*)p; p += 134217728;     // [256*512, 256] bf16 hi (full sequence)
    u16* xl  = (u16*)p; p += 134217728;
    u16* wth = (u16*)p; p += 3145728;       // [2048, 768] bf16 hi (transposed W4)
    u16* wtl = (u16*)p; p += 3145728;
    u16* hh  = (u16*)p; p += 6291456;       // [12, 512, 512] bf16 hi
    u16* hl  = (u16*)p; p += 6291456;
    float* bias4 = (float*)p; p += 8192;    // [2048]
    float* cb    = (float*)p; p += 4096;    // [2][512] carry double-buffer
    float* lg    = (float*)p; p += 50331648;// [12*512, 2048] fp32 logits
    // total ~322 MiB (ws poison shows 512 MiB available)

    init_k<<<12288, 256, 0, stream>>>(hh, hl, cb);
    pack_w<<<6144, 256, 0, stream>>>(Wf, bf_, Wi, bi_, Wo, bo_, Wg, bg_, wth, wtl, bias4);
    split_x<<<32768, 256, 0, stream>>>(x, xh, xl);

    for (int blk = 0; blk < 22; ++blk) {
        int t0 = blk * 12;
        int S = (256 - t0 >= 12) ? 12 : (256 - t0);  // last block: 4 steps
        gemm_x3<<<dim3(16, S * 4), 256, 0, stream>>>(
            xh + (size_t)t0 * 512 * 256, xl + (size_t)t0 * 512 * 256,
            hh, hl, wth, wtl, bias4, lg);
        gates_k<<<S * 128, 256, 0, stream>>>(lg, cb, hh, hl, out, t0, S, blk & 1, (blk + 1) & 1);
    }
}

// Round 3
// 1975.417 us; speedup vs baseline: 1.2152x; 1.0902x over previous
//
#include <hip/hip_runtime.h>

typedef unsigned short u16;
typedef unsigned int   u32;

typedef __attribute__((ext_vector_type(8))) short bf16x8;
typedef __attribute__((ext_vector_type(16))) float f32x16;

// ---------- helpers ----------
__device__ __forceinline__ u16 f2bf(float v) {           // RNE fp32 -> bf16
    u32 u = __float_as_uint(v);
    u32 r = (u + 0x7fffu + ((u >> 16) & 1u)) >> 16;
    return (u16)r;
}
__device__ __forceinline__ float bf2f(u16 h) { return __uint_as_float(((u32)h) << 16); }

__device__ __forceinline__ float ftanh(float x) {        // tanh via exp, ~5 inst
    float e = __expf(2.0f * x);                          // inf for large x -> rcp gives 0 -> +1
    return 1.0f - 2.0f * __builtin_amdgcn_rcpf(e + 1.0f);
}

__device__ __forceinline__ void gl2lds16(const void* g, void* l) {
    __builtin_amdgcn_global_load_lds(
        (const __attribute__((address_space(1))) void*)g,
        (__attribute__((address_space(3))) void*)l, 16, 0, 0);
}

// ---------- init: zero h buffers and carry ----------
__global__ void init_k(u16* __restrict__ hh, u16* __restrict__ hl, float* __restrict__ cb) {
    int i = blockIdx.x * 256 + threadIdx.x;           // grid covers 12*512*512
    hh[i] = 0; hl[i] = 0;
    if (i < 2 * 512) cb[i] = 0.0f;
}

// ---------- pack W: W4t[n][k] = W_gate[k][col], hi/lo bf16 split; bias4[n] ----------
__global__ void pack_w(const float* __restrict__ Wf, const float* __restrict__ bf_,
                       const float* __restrict__ Wi, const float* __restrict__ bi_,
                       const float* __restrict__ Wo, const float* __restrict__ bo_,
                       const float* __restrict__ Wg, const float* __restrict__ bg_,
                       u16* __restrict__ wth, u16* __restrict__ wtl, float* __restrict__ bias4) {
    int idx = blockIdx.x * 256 + threadIdx.x;         // 2048*768 threads, wave-uniform n (768=12*64)
    int n = idx / 768, k = idx - n * 768;
    int gate = n >> 9, col = n & 511;
    const float* W = (gate == 0) ? Wf : (gate == 1) ? Wi : (gate == 2) ? Wo : Wg;
    float v = W[k * 512 + col];
    u16 h = f2bf(v);
    wth[idx] = h;
    wtl[idx] = f2bf(v - bf2f(h));
    if (k == 0) {
        const float* bb = (gate == 0) ? bf_ : (gate == 1) ? bi_ : (gate == 2) ? bo_ : bg_;
        bias4[n] = bb[col];
    }
}

// ---------- split ALL x to hi/lo bf16 (hoisted out of the block loop) ----------
__global__ void split_x(const float* __restrict__ src, u16* __restrict__ oh, u16* __restrict__ ol) {
    int i = blockIdx.x * 256 + threadIdx.x;           // grid covers 256*512*256/4
    float4 v = ((const float4*)src)[i];
    u16 hx = f2bf(v.x), hy = f2bf(v.y), hz = f2bf(v.z), hw = f2bf(v.w);
    u16 lx = f2bf(v.x - bf2f(hx)), ly = f2bf(v.y - bf2f(hy));
    u16 lz = f2bf(v.z - bf2f(hz)), lw = f2bf(v.w - bf2f(hw));
    uint2 hv; hv.x = (u32)hx | ((u32)hy << 16); hv.y = (u32)hz | ((u32)hw << 16);
    uint2 lv; lv.x = (u32)lx | ((u32)ly << 16); lv.y = (u32)lz | ((u32)lw << 16);
    ((uint2*)oh)[i] = hv;
    ((uint2*)ol)[i] = lv;
}

// ---------- bf16x3 GEMM: logits[m][n] = A[m][:]@W4[:, n] + bias4[n] ----------
// A[m][k<256]=x[t][b][k], A[m][256+k]=h_buf[s][b][k]; m=(s,b); 128x128 tile, BK=32
// 32x32x16 MFMA: 24 mfma + 16 ds_read_b128 per wave per K-iter.
// grid x = bm (48 = 0 mod 8) so all 16 bn-readers of one A-slice share an XCD L2.
#define BK 32
__global__ __launch_bounds__(256, 3) void gemm_x3(
    const u16* __restrict__ xh, const u16* __restrict__ xl,
    const u16* __restrict__ hh, const u16* __restrict__ hl,
    const u16* __restrict__ wth, const u16* __restrict__ wtl,
    const float* __restrict__ bias4, float* __restrict__ lg) {
    __shared__ __align__(16) u16 Ah[128 * BK];
    __shared__ __align__(16) u16 Al[128 * BK];
    __shared__ __align__(16) u16 Bh[128 * BK];
    __shared__ __align__(16) u16 Bl[128 * BK];

    const int tid = threadIdx.x;
    const int wid = tid >> 6, lane = tid & 63;
    const int bm = blockIdx.x, bn = blockIdx.y;       // x = bm for XCD A-locality
    const int s = bm >> 2;                 // t%12 == s (t0 always multiple of 12)
    const int b0 = (bm & 3) * 128;
    const int laneR = lane >> 2;           // row within 16-row staging group
    const int laneC = (lane & 3) * 8;      // k element offset

    u16* lds = (wid == 0) ? Ah : (wid == 1) ? Al : (wid == 2) ? Bh : Bl;
    const u16* xp = (wid == 0) ? xh : xl;
    const u16* hp = (wid == 0) ? hh : hl;
    const u16* wp = (wid == 2) ? wth : wtl;
    const u16* xrow = xp + (size_t)(s * 512 + b0) * 256 + laneR * 256 + laneC;
    const u16* hrow = hp + (size_t)(s * 512 + b0) * 512 + laneR * 512 + laneC;
    const u16* wrow = wp + (size_t)(bn * 128) * 768 + laneR * 768 + laneC;

    const int wm = wid >> 1, wn = wid & 1;
    const int l32 = lane & 31, khalf = lane >> 5;     // A/B frag: row = lane&31, k = khalf*8+j

    f32x16 acc[2][2];
#pragma unroll
    for (int i = 0; i < 2; i++)
#pragma unroll
        for (int j = 0; j < 2; j++)
#pragma unroll
            for (int r = 0; r < 16; ++r) acc[i][j][r] = 0.f;

    for (int k0 = 0; k0 < 768; k0 += BK) {
        __syncthreads();
        if (wid < 2) {
            if (k0 < 256) {
                const u16* src = xrow + k0;
#pragma unroll
                for (int r = 0; r < 8; ++r) gl2lds16(src + r * 16 * 256, lds + r * 16 * BK);
            } else {
                const u16* src = hrow + (k0 - 256);
#pragma unroll
                for (int r = 0; r < 8; ++r) gl2lds16(src + r * 16 * 512, lds + r * 16 * BK);
            }
        } else {
            const u16* src = wrow + k0;
#pragma unroll
            for (int r = 0; r < 8; ++r) gl2lds16(src + r * 16 * 768, lds + r * 16 * BK);
        }
        __syncthreads();

        bf16x8 a_h[2][2], a_l[2][2], b_h[2][2], b_l[2][2];   // [tile][k-step]
#pragma unroll
        for (int t = 0; t < 2; ++t)
#pragma unroll
            for (int ks = 0; ks < 2; ++ks) {
                int ko = ks * 16 + khalf * 8;
                a_h[t][ks] = *(const bf16x8*)&Ah[(wm * 64 + t * 32 + l32) * BK + ko];
                a_l[t][ks] = *(const bf16x8*)&Al[(wm * 64 + t * 32 + l32) * BK + ko];
                b_h[t][ks] = *(const bf16x8*)&Bh[(wn * 64 + t * 32 + l32) * BK + ko];
                b_l[t][ks] = *(const bf16x8*)&Bl[(wn * 64 + t * 32 + l32) * BK + ko];
            }
#pragma unroll
        for (int ks = 0; ks < 2; ++ks)
#pragma unroll
            for (int i = 0; i < 2; ++i)
#pragma unroll
                for (int j = 0; j < 2; ++j) {
                    acc[i][j] = __builtin_amdgcn_mfma_f32_32x32x16_bf16(a_h[i][ks], b_h[j][ks], acc[i][j], 0, 0, 0);
                    acc[i][j] = __builtin_amdgcn_mfma_f32_32x32x16_bf16(a_h[i][ks], b_l[j][ks], acc[i][j], 0, 0, 0);
                    acc[i][j] = __builtin_amdgcn_mfma_f32_32x32x16_bf16(a_l[i][ks], b_h[j][ks], acc[i][j], 0, 0, 0);
                }
    }

    // C/D layout (measured): col = lane&31, row = (reg&3) + 8*(reg>>2) + 4*(lane>>5)
#pragma unroll
    for (int j = 0; j < 2; ++j) {
        int n = bn * 128 + wn * 64 + j * 32 + l32;
        float bv = bias4[n];
#pragma unroll
        for (int i = 0; i < 2; ++i) {
            int rbase = wm * 64 + i * 32 + 4 * khalf;
#pragma unroll
            for (int r = 0; r < 16; ++r) {
                int row = rbase + (r & 3) + 8 * (r >> 2);
                __builtin_nontemporal_store(acc[i][j][r] + bv,
                    &lg[(size_t)(bm * 128 + row) * 2048 + n]);
            }
        }
    }
}

// ---------- one sequential chain step: r <- tanh(softmax_f[rowb]*r + softmax_i[rowb]*tanh(g[rowb])) ----------
__device__ __forceinline__ void chain_step(const float* __restrict__ lg, int j, int lane, float r[8]) {
    int rowb = (j + 1) % 12;   // batch row (t+1)%P of c_t (t0 always multiple of 12)
    const float* base = lg + (size_t)(j * 512 + rowb) * 2048 + lane * 8;
    float f[8], iv[8], g[8];
#pragma unroll
    for (int u = 0; u < 8; ++u) { f[u] = base[u]; iv[u] = base[512 + u]; g[u] = base[1536 + u]; }
    float mf = -1e30f, mi = -1e30f;
#pragma unroll
    for (int u = 0; u < 8; ++u) { mf = fmaxf(mf, f[u]); mi = fmaxf(mi, iv[u]); }
#pragma unroll
    for (int o = 32; o; o >>= 1) { mf = fmaxf(mf, __shfl_xor(mf, o)); mi = fmaxf(mi, __shfl_xor(mi, o)); }
    float sf = 0.f, si = 0.f;
#pragma unroll
    for (int u = 0; u < 8; ++u) {
        f[u] = __expf(f[u] - mf); sf += f[u];
        iv[u] = __expf(iv[u] - mi); si += iv[u];
    }
#pragma unroll
    for (int o = 32; o; o >>= 1) { sf += __shfl_xor(sf, o); si += __shfl_xor(si, o); }
    float rf = __builtin_amdgcn_rcpf(sf), ri = __builtin_amdgcn_rcpf(si);
#pragma unroll
    for (int u = 0; u < 8; ++u) {
        float gg = ftanh(g[u]);
        r[u] = ftanh(f[u] * rf * r[u] + iv[u] * ri * gg);
    }
}

// ---------- gates (chain fused): wave 0 walks chain to its block's s; then all waves do
//            softmax f,i,o + tanh g, c_new, h row (hi/lo bf16), final out ----------
// s reversed vs blockIdx so the longest redundant chains dispatch FIRST and overlap the bulk.
__global__ __launch_bounds__(256) void gates_k(
    const float* __restrict__ lg, float* __restrict__ cb,
    u16* __restrict__ hh, u16* __restrict__ hl,
    float* __restrict__ out, int t0, int S, int rd, int wr) {
    __shared__ float rsh[512];
    const int widx = threadIdx.x >> 6, lane = threadIdx.x & 63;
    const int s = (S - 1) - (blockIdx.x >> 7);          // 128 blocks per s, longest chain first
    const int b = (blockIdx.x & 127) * 4 + widx;
    const int t = t0 + s;

    if (widx == 0) {
        float r[8];
#pragma unroll
        for (int u = 0; u < 8; ++u) r[u] = cb[rd * 512 + lane * 8 + u];
        for (int j = 0; j < s; ++j) chain_step(lg, j, lane, r);   // identical op sequence in every block -> bitwise-identical r
#pragma unroll
        for (int u = 0; u < 8; ++u) rsh[lane * 8 + u] = r[u];
        // carrier block (s == S-1, early dispatch) extends the chain one step, writes next-launch carry
        if ((int)blockIdx.x == 127 && t0 + S < 256) {
            chain_step(lg, S - 1, lane, r);
#pragma unroll
            for (int u = 0; u < 8; ++u) cb[wr * 512 + lane * 8 + u] = r[u];
        }
    }
    __syncthreads();

    const float* row = lg + (size_t)(s * 512 + b) * 2048 + lane * 8;
    float f[8], iv[8], ov[8], g[8];
#pragma unroll
    for (int u = 0; u < 8; ++u) {
        f[u] = row[u]; iv[u] = row[512 + u]; ov[u] = row[1024 + u]; g[u] = row[1536 + u];
    }
    float mf = -1e30f, mi = -1e30f, mo = -1e30f;
#pragma unroll
    for (int u = 0; u < 8; ++u) { mf = fmaxf(mf, f[u]); mi = fmaxf(mi, iv[u]); mo = fmaxf(mo, ov[u]); }
#pragma unroll
    for (int o = 32; o; o >>= 1) {
        mf = fmaxf(mf, __shfl_xor(mf, o));
        mi = fmaxf(mi, __shfl_xor(mi, o));
        mo = fmaxf(mo, __shfl_xor(mo, o));
    }
    float sf = 0.f, si = 0.f, so = 0.f;
#pragma unroll
    for (int u = 0; u < 8; ++u) {
        f[u] = __expf(f[u] - mf); sf += f[u];
        iv[u] = __expf(iv[u] - mi); si += iv[u];
        ov[u] = __expf(ov[u] - mo); so += ov[u];
    }
#pragma unroll
    for (int o = 32; o; o >>= 1) {
        sf += __shfl_xor(sf, o); si += __shfl_xor(si, o); so += __shfl_xor(so, o);
    }
    float rf = __builtin_amdgcn_rcpf(sf), ri = __builtin_amdgcn_rcpf(si), ro = __builtin_amdgcn_rcpf(so);
    float hout[8];
#pragma unroll
    for (int u = 0; u < 8; ++u) {
        float rr = rsh[lane * 8 + u];
        float gg = ftanh(g[u]);
        float cv = ftanh(f[u] * rf * rr + iv[u] * ri * gg);
        hout[u] = ov[u] * ro * cv;
    }
    u32 hhp[4], hlp[4];
#pragma unroll
    for (int u = 0; u < 4; ++u) {
        u16 h0 = f2bf(hout[2 * u]), h1 = f2bf(hout[2 * u + 1]);
        u16 l0 = f2bf(hout[2 * u] - bf2f(h0)), l1 = f2bf(hout[2 * u + 1] - bf2f(h1));
        hhp[u] = (u32)h0 | ((u32)h1 << 16);
        hlp[u] = (u32)l0 | ((u32)l1 << 16);
    }
    size_t hb = ((size_t)(s * 512 + b)) * 512 + lane * 8;   // h row index = t%12 = s
    *(uint4*)&hh[hb] = make_uint4(hhp[0], hhp[1], hhp[2], hhp[3]);
    *(uint4*)&hl[hb] = make_uint4(hlp[0], hlp[1], hlp[2], hlp[3]);
    if (t == 255) {
        float* op = out + (size_t)b * 512 + lane * 8;
#pragma unroll
        for (int u = 0; u < 8; ++u) op[u] = hout[u];
    }
}

extern "C" void kernel_launch(void* const* d_in, const int* in_sizes, int n_in,
                              void* d_out, int out_size, void* d_ws, size_t ws_size,
                              hipStream_t stream) {
    const float* x   = (const float*)d_in[0];
    const float* Wf  = (const float*)d_in[1];
    const float* bf_ = (const float*)d_in[2];
    const float* Wi  = (const float*)d_in[3];
    const float* bi_ = (const float*)d_in[4];
    const float* Wo  = (const float*)d_in[5];
    const float* bo_ = (const float*)d_in[6];
    const float* Wg  = (const float*)d_in[7];
    const float* bg_ = (const float*)d_in[8];
    float* out = (float*)d_out;

    char* p = (char*)d_ws;
    u16* xh  = (u16*)p; p += 134217728;     // [256*512, 256] bf16 hi (full sequence)
    u16* xl  = (u16*)p; p += 134217728;
    u16* wth = (u16*)p; p += 3145728;       // [2048, 768] bf16 hi (transposed W4)
    u16* wtl = (u16*)p; p += 3145728;
    u16* hh  = (u16*)p; p += 6291456;       // [12, 512, 512] bf16 hi
    u16* hl  = (u16*)p; p += 6291456;
    float* bias4 = (float*)p; p += 8192;    // [2048]
    float* cb    = (float*)p; p += 4096;    // [2][512] carry double-buffer
    float* lg    = (float*)p; p += 50331648;// [12*512, 2048] fp32 logits
    // total ~322 MiB (ws poison shows 512 MiB available)

    init_k<<<12288, 256, 0, stream>>>(hh, hl, cb);
    pack_w<<<6144, 256, 0, stream>>>(Wf, bf_, Wi, bi_, Wo, bo_, Wg, bg_, wth, wtl, bias4);
    split_x<<<32768, 256, 0, stream>>>(x, xh, xl);

    for (int blk = 0; blk < 22; ++blk) {
        int t0 = blk * 12;
        int S = (256 - t0 >= 12) ? 12 : (256 - t0);  // last block: 4 steps
        gemm_x3<<<dim3(S * 4, 16), 256, 0, stream>>>(   // x = bm: A-slice readers share an XCD
            xh + (size_t)t0 * 512 * 256, xl + (size_t)t0 * 512 * 256,
            hh, hl, wth, wtl, bias4, lg);
        gates_k<<<S * 128, 256, 0, stream>>>(lg, cb, hh, hl, out, t0, S, blk & 1, (blk + 1) & 1);
    }
}